// Round 8
// baseline (409.889 us; speedup 1.0000x reference)
//
#include <hip/hip_runtime.h>
#include <hip/hip_cooperative_groups.h>
#include <math.h>

namespace cg = cooperative_groups;

#if defined(__has_builtin)
#  if __has_builtin(__builtin_amdgcn_exp2f)
#    define EXP2F(x) __builtin_amdgcn_exp2f(x)
#  endif
#  if __has_builtin(__builtin_amdgcn_rcpf)
#    define RCPF(x) __builtin_amdgcn_rcpf(x)
#  endif
#endif
#ifndef EXP2F
#  define EXP2F(x) exp2f(x)
#endif
#ifndef RCPF
#  define RCPF(x) (1.0f/(x))
#endif

static constexpr int Bn = 16, QN = 512, KN = 512, Hn = 64, DV = 256, DIN = 256;
static constexpr int TQ = 8;
static constexpr float TWO_LOG2E = 2.8853900817779268f;  // 2*log2(e)
static constexpr float LOG2E     = 1.4426950408889634f;

typedef __attribute__((ext_vector_type(8))) short short8;  // 8 bf16
typedef __attribute__((ext_vector_type(4))) float f32x4;

__device__ __forceinline__ short f2bf(float x) {          // RNE fp32->bf16
  unsigned u = __builtin_bit_cast(unsigned, x);
  u += 0x7FFF + ((u >> 16) & 1);
  return (short)(u >> 16);
}
__device__ __forceinline__ float bf2f(short h) {
  return __builtin_bit_cast(float, ((unsigned)(unsigned short)h) << 16);
}

// Shared-memory overlays (phases are barrier-separated).
struct AttnS {
  float qes2[Hn][TQ];     // 2 KB   [h][r] broadcast layout
  float pt[KN][12];       // 24 KB  stride 12: 16B-aligned, 0 conflicts
  float pacc[TQ][DV];     // 8 KB   upper-half PV partials
  float wsum[8][TQ];
  float inv_s[TQ];
};                        // 35104 B -> 4 blocks/CU (140.4 of 160 KB)
struct ProjS { float tr[8][16][20]; };   // 10240 B, overlaid

// ---- phase 0: W -> bf16 hi/lo (one-time; removes per-block conversion) ----
__device__ __forceinline__ void prep_phase(
    int blk, int t, const float* Wq, const float* Wk,
    ushort* wqh, ushort* wql, ushort* wkh, ushort* wkl)
{
  int i = blk * 512 + t;                   // blk in [0,32) -> 16384 elements
  float xq = Wq[i];
  short hq = f2bf(xq);
  wqh[i] = (ushort)hq; wql[i] = (ushort)f2bf(xq - bf2f(hq));
  float xk = Wk[i];
  short hk = f2bf(xk);
  wkh[i] = (ushort)hk; wkl[i] = (ushort)f2bf(xk - bf2f(hk));
}

// ---- phase 1: projections via MFMA, 3-pass bf16 hi/lo (R7 guts, verified).
// blk in [0,512); 8 waves = two 16-row tiles (waves 0-3 / 4-7), wave = one
// 16x16 col-tile. exp2 fused; ekT transposed through wave-private LDS tile.
__device__ __forceinline__ void proj_phase(
    char* smem, int blk, int t,
    const float* queries, const float* keys,
    const ushort* wqh, const ushort* wql,
    const ushort* wkh, const ushort* wkl,
    float* qe, float* ekT)
{
  ProjS& P = *reinterpret_cast<ProjS*>(smem);
  int lane = t & 63, wid = t >> 6;
  int sub = wid >> 2, wid4 = wid & 3;
  int tile = blk * 2 + sub;                // 0..1023
  bool is_k = tile >= 512;
  int trow = (tile & 511) * 16;
  const float*  X  = is_k ? keys : queries;
  const ushort* Wh = is_k ? wkh : wqh;
  const ushort* Wl = is_k ? wkl : wql;
  int mr = lane & 15, quad = lane >> 4;
  const float*  xp  = X  + (size_t)(trow + mr) * DIN + quad * 8;
  const ushort* whp = Wh + (size_t)(wid4 * 16 + mr) * DIN + quad * 8;
  const ushort* wlp = Wl + (size_t)(wid4 * 16 + mr) * DIN + quad * 8;

  f32x4 acc = (f32x4){0.f, 0.f, 0.f, 0.f};
  #pragma unroll
  for (int kc = 0; kc < 8; ++kc) {
    float4 a0 = *(const float4*)(xp + kc * 32);
    float4 a1 = *(const float4*)(xp + kc * 32 + 4);
    float av[8] = {a0.x, a0.y, a0.z, a0.w, a1.x, a1.y, a1.z, a1.w};
    short8 ah, al;
    #pragma unroll
    for (int j = 0; j < 8; ++j) {
      ah[j] = f2bf(av[j]);
      al[j] = f2bf(av[j] - bf2f(ah[j]));
    }
    short8 bh = *(const short8*)(whp + kc * 32);
    short8 bl = *(const short8*)(wlp + kc * 32);
    acc = __builtin_amdgcn_mfma_f32_16x16x32_bf16(al, bh, acc, 0, 0, 0);
    acc = __builtin_amdgcn_mfma_f32_16x16x32_bf16(ah, bl, acc, 0, 0, 0);
    acc = __builtin_amdgcn_mfma_f32_16x16x32_bf16(ah, bh, acc, 0, 0, 0);
  }
  // C/D: col = lane&15, row = quad*4 + reg  [verified R4-R7]
  if (!is_k) {
    #pragma unroll
    for (int reg = 0; reg < 4; ++reg) {
      int row = trow + quad * 4 + reg;
      qe[(size_t)row * Hn + wid4 * 16 + mr] = EXP2F(acc[reg] * TWO_LOG2E);
    }
  } else {
    #pragma unroll
    for (int reg = 0; reg < 4; ++reg)      // wave-private: no barrier needed
      P.tr[wid][mr][quad * 4 + reg] = EXP2F(acc[reg] * TWO_LOG2E);
    int b = trow >> 9, kr = trow & (KN - 1);
    #pragma unroll
    for (int hp = 0; hp < 4; ++hp) {
      int h_l = hp * 4 + quad, k_l = mr;
      ekT[((size_t)b * Hn + wid4 * 16 + h_l) * KN + kr + k_l] = P.tr[wid][h_l][k_l];
    }
  }
}

// ---- phase 2: fused attention (R6 guts verbatim: the 61us configuration).
// tanh(q+k) = 1 - 2/(Eq*Ek+1): fma+rcp+fma; softmax w/o max-subtraction
// (|score| <= sum|wv| ~ 7); PV 2-way k-split, col-per-thread.
__device__ __forceinline__ void attn_phase(
    char* smem, int blk, int t,
    const float* qe, const float* ekT, const float* values,
    const int* valid_lens, const float* wv, float* out)
{
  AttnS& S = *reinterpret_cast<AttnS*>(smem);
  int b = blk >> 6;
  int q0 = (blk & 63) * TQ;
  int L = valid_lens[b];
  int lane = t & 63, wave = t >> 6;

  S.qes2[t >> 3][t & 7] = qe[(size_t)(b * QN + q0 + (t & 7)) * Hn + (t >> 3)];
  __syncthreads();

  float Ssum = 0.f;
  #pragma unroll
  for (int h = 0; h < Hn; ++h) Ssum += wv[h];

  {  // scores: thread owns k = t
    int k = t;
    float p[TQ];
    if (k < L) {
      float sc[TQ];
      #pragma unroll
      for (int r = 0; r < TQ; ++r) sc[r] = Ssum;
      const float* kb = ekT + (size_t)b * Hn * KN + k;
      for (int h0 = 0; h0 < Hn; h0 += 8) {
        float ekv[8];
        #pragma unroll
        for (int j = 0; j < 8; ++j)              // 8 loads in flight
          ekv[j] = kb[(size_t)(h0 + j) * KN];
        #pragma unroll
        for (int j = 0; j < 8; ++j) {
          int h = h0 + j;
          float w2 = 2.0f * wv[h];
          float4 qa = *(const float4*)&S.qes2[h][0];
          float4 qb = *(const float4*)&S.qes2[h][4];
          float ek = ekv[j];
          sc[0] -= w2 * RCPF(qa.x * ek + 1.0f);
          sc[1] -= w2 * RCPF(qa.y * ek + 1.0f);
          sc[2] -= w2 * RCPF(qa.z * ek + 1.0f);
          sc[3] -= w2 * RCPF(qa.w * ek + 1.0f);
          sc[4] -= w2 * RCPF(qb.x * ek + 1.0f);
          sc[5] -= w2 * RCPF(qb.y * ek + 1.0f);
          sc[6] -= w2 * RCPF(qb.z * ek + 1.0f);
          sc[7] -= w2 * RCPF(qb.w * ek + 1.0f);
        }
      }
      #pragma unroll
      for (int r = 0; r < TQ; ++r) p[r] = EXP2F(sc[r] * LOG2E);
      *(float4*)&S.pt[k][0] = make_float4(p[0], p[1], p[2], p[3]);
      *(float4*)&S.pt[k][4] = make_float4(p[4], p[5], p[6], p[7]);
    } else {
      #pragma unroll
      for (int r = 0; r < TQ; ++r) p[r] = 0.f;
    }
    #pragma unroll
    for (int r = 0; r < TQ; ++r) {               // in-register row sums
      float s = p[r];
      #pragma unroll
      for (int off = 32; off > 0; off >>= 1) s += __shfl_xor(s, off, 64);
      if (lane == r) S.wsum[wave][r] = s;
    }
  }
  __syncthreads();
  if (t < TQ) {
    float s = 0.f;
    #pragma unroll
    for (int w = 0; w < 8; ++w) s += S.wsum[w][t];
    S.inv_s[t] = 1.0f / s;                       // read after the pacc barrier
  }

  // PV: thread owns col c = t&255, half of k (t>>8)
  int c = t & (DV - 1), half = t >> 8;
  int mid = L >> 1;
  int k0 = half ? mid : 0;
  int k1 = half ? L : mid;
  float acc[TQ];
  #pragma unroll
  for (int r = 0; r < TQ; ++r) acc[r] = 0.f;
  const float* vb = values + (size_t)b * KN * DV + c;
  #pragma unroll 4
  for (int k = k0; k < k1; ++k) {
    float val = vb[(size_t)k * DV];              // coalesced
    float4 pa = *(const float4*)&S.pt[k][0];     // same addr all lanes: broadcast
    float4 pb = *(const float4*)&S.pt[k][4];
    acc[0] += pa.x * val; acc[1] += pa.y * val;
    acc[2] += pa.z * val; acc[3] += pa.w * val;
    acc[4] += pb.x * val; acc[5] += pb.y * val;
    acc[6] += pb.z * val; acc[7] += pb.w * val;
  }
  if (half) {
    #pragma unroll
    for (int r = 0; r < TQ; ++r) S.pacc[r][c] = acc[r];
  }
  __syncthreads();
  if (!half) {
    float* ob = out + (size_t)(b * QN + q0) * DV + c;
    #pragma unroll
    for (int r = 0; r < TQ; ++r)
      ob[(size_t)r * DV] = (acc[r] + S.pacc[r][c]) * S.inv_s[r];
  }
}

// ---- single cooperative kernel: prep -> proj -> attn, 1024 x 512 ----
__global__ __launch_bounds__(512, 8) void mega_kernel(
    const float* queries, const float* keys, const float* values,
    const int* valid_lens, const float* Wq, const float* Wk, const float* wv,
    ushort* wqh, ushort* wql, ushort* wkh, ushort* wkl,
    float* qe, float* ekT, float* out)
{
  __shared__ __align__(16) char smem[sizeof(AttnS)];
  cg::grid_group grid = cg::this_grid();
  int t = threadIdx.x, blk = blockIdx.x;

  if (blk < 32) prep_phase(blk, t, Wq, Wk, wqh, wql, wkh, wkl);
  grid.sync();
  if (blk < 512)
    proj_phase(smem, blk, t, queries, keys, wqh, wql, wkh, wkl, qe, ekT);
  grid.sync();
  attn_phase(smem, blk, t, qe, ekT, values, valid_lens, wv, out);
}

// ---- fallback path: same phases as 3 normal kernels ----
__global__ __launch_bounds__(512) void prep_k(
    const float* Wq, const float* Wk,
    ushort* wqh, ushort* wql, ushort* wkh, ushort* wkl)
{
  prep_phase(blockIdx.x, threadIdx.x, Wq, Wk, wqh, wql, wkh, wkl);
}
__global__ __launch_bounds__(512) void proj_k(
    const float* queries, const float* keys,
    const ushort* wqh, const ushort* wql,
    const ushort* wkh, const ushort* wkl,
    float* qe, float* ekT)
{
  __shared__ __align__(16) char smem[sizeof(ProjS)];
  proj_phase(smem, blockIdx.x, threadIdx.x, queries, keys,
             wqh, wql, wkh, wkl, qe, ekT);
}
__global__ __launch_bounds__(512) void attn_k(
    const float* qe, const float* ekT, const float* values,
    const int* valid_lens, const float* wv, float* out)
{
  __shared__ __align__(16) char smem[sizeof(AttnS)];
  attn_phase(smem, blockIdx.x, threadIdx.x, qe, ekT, values,
             valid_lens, wv, out);
}

extern "C" void kernel_launch(void* const* d_in, const int* in_sizes, int n_in,
                              void* d_out, int out_size, void* d_ws, size_t ws_size,
                              hipStream_t stream) {
  const float* queries    = (const float*)d_in[0];
  const float* keys       = (const float*)d_in[1];
  const float* values     = (const float*)d_in[2];
  const int*   valid_lens = (const int*)d_in[3];
  const float* Wq         = (const float*)d_in[4];
  const float* Wk         = (const float*)d_in[5];
  const float* wv         = (const float*)d_in[6];
  float* out = (float*)d_out;

  char* ws = (char*)d_ws;
  float*  qe  = (float*)ws;                          // [8192][64] = 2 MB
  float*  ekT = qe + (size_t)Bn * QN * Hn;           // [B,64,512] = 2 MB
  ushort* wqh = (ushort*)(ekT + (size_t)Bn * Hn * KN);
  ushort* wql = wqh + Hn * DIN;                      // 4 x 32 KB
  ushort* wkh = wql + Hn * DIN;
  ushort* wkl = wkh + Hn * DIN;

  void* args[] = {
    (void*)&queries, (void*)&keys, (void*)&values, (void*)&valid_lens,
    (void*)&Wq, (void*)&Wk, (void*)&wv,
    (void*)&wqh, (void*)&wql, (void*)&wkh, (void*)&wkl,
    (void*)&qe, (void*)&ekT, (void*)&out,
  };
  hipError_t err = hipLaunchCooperativeKernel(
      (const void*)mega_kernel, dim3(1024), dim3(512), args, 0, stream);
  if (err != hipSuccess) {
    // graceful fallback: identical phases, normal launches
    prep_k<<<32, 512, 0, stream>>>(Wq, Wk, wqh, wql, wkh, wkl);
    proj_k<<<512, 512, 0, stream>>>(queries, keys, wqh, wql, wkh, wkl, qe, ekT);
    attn_k<<<1024, 512, 0, stream>>>(qe, ekT, values, valid_lens, wv, out);
  }
}

// Round 9
// 149.519 us; speedup vs baseline: 2.7414x; 2.7414x over previous
//
#include <hip/hip_runtime.h>
#include <math.h>

#if defined(__has_builtin)
#  if __has_builtin(__builtin_amdgcn_exp2f)
#    define EXP2F(x) __builtin_amdgcn_exp2f(x)
#  endif
#  if __has_builtin(__builtin_amdgcn_rcpf)
#    define RCPF(x) __builtin_amdgcn_rcpf(x)
#  endif
#endif
#ifndef EXP2F
#  define EXP2F(x) exp2f(x)
#endif
#ifndef RCPF
#  define RCPF(x) (1.0f/(x))
#endif

static constexpr int Bn = 16, QN = 512, KN = 512, Hn = 64, DV = 256, DIN = 256;
static constexpr int TQ = 8;
static constexpr float TWO_LOG2E = 2.8853900817779268f;  // 2*log2(e)
static constexpr float LOG2E     = 1.4426950408889634f;

typedef __attribute__((ext_vector_type(8))) short short8;  // 8 bf16
typedef __attribute__((ext_vector_type(4))) float f32x4;

__device__ __forceinline__ short f2bf(float x) {          // RNE fp32->bf16
  unsigned u = __builtin_bit_cast(unsigned, x);
  u += 0x7FFF + ((u >> 16) & 1);
  return (short)(u >> 16);
}
__device__ __forceinline__ float bf2f(short h) {
  return __builtin_bit_cast(float, ((unsigned)(unsigned short)h) << 16);
}

// One-time W pack: f32 -> bf16 hi/lo, row-major [h][k] (B-fragment = one dwordx4).
__global__ __launch_bounds__(256) void prep_kernel(
    const float* __restrict__ Wq, const float* __restrict__ Wk,
    ushort* __restrict__ wqh, ushort* __restrict__ wql,
    ushort* __restrict__ wkh, ushort* __restrict__ wkl)
{
  int i = blockIdx.x * 256 + threadIdx.x;     // 64 blocks -> 16384
  float xq = Wq[i];
  short hq = f2bf(xq);
  wqh[i] = (ushort)hq; wql[i] = (ushort)f2bf(xq - bf2f(hq));
  float xk = Wk[i];
  short hk = f2bf(xk);
  wkh[i] = (ushort)hk; wkl[i] = (ushort)f2bf(xk - bf2f(hk));
}

// Projections via MFMA, 3-pass bf16 hi/lo (R7 verbatim — verified numerics,
// and R8's accounting showed this chain is ~0-6us, not the 50-90us residue
// I had misattributed to it). 1024 blocks x 4 waves, wave = one 16x16 tile.
__global__ __launch_bounds__(256) void proj_mfma(
    const float* __restrict__ queries, const float* __restrict__ keys,
    const ushort* __restrict__ wqh, const ushort* __restrict__ wql,
    const ushort* __restrict__ wkh, const ushort* __restrict__ wkl,
    float* __restrict__ qe, float* __restrict__ ekT)
{
  __shared__ float tr[4][16][20];                // 5.1 KB transpose tiles
  int t = threadIdx.x;
  int lane = t & 63, wid = t >> 6;
  bool is_k = blockIdx.x >= 512;
  int trow = (blockIdx.x & 511) * 16;
  const float*  X  = is_k ? keys : queries;
  const ushort* Wh = is_k ? wkh : wqh;
  const ushort* Wl = is_k ? wkl : wql;
  int mr = lane & 15, quad = lane >> 4;
  const float*  xp  = X  + (size_t)(trow + mr) * DIN + quad * 8;
  const ushort* whp = Wh + (size_t)(wid * 16 + mr) * DIN + quad * 8;
  const ushort* wlp = Wl + (size_t)(wid * 16 + mr) * DIN + quad * 8;

  f32x4 acc = (f32x4){0.f, 0.f, 0.f, 0.f};
  #pragma unroll
  for (int kc = 0; kc < 8; ++kc) {
    float4 a0 = *(const float4*)(xp + kc * 32);
    float4 a1 = *(const float4*)(xp + kc * 32 + 4);
    float av[8] = {a0.x, a0.y, a0.z, a0.w, a1.x, a1.y, a1.z, a1.w};
    short8 ah, al;
    #pragma unroll
    for (int j = 0; j < 8; ++j) {
      ah[j] = f2bf(av[j]);
      al[j] = f2bf(av[j] - bf2f(ah[j]));
    }
    short8 bh = *(const short8*)(whp + kc * 32);
    short8 bl = *(const short8*)(wlp + kc * 32);
    acc = __builtin_amdgcn_mfma_f32_16x16x32_bf16(al, bh, acc, 0, 0, 0);
    acc = __builtin_amdgcn_mfma_f32_16x16x32_bf16(ah, bl, acc, 0, 0, 0);
    acc = __builtin_amdgcn_mfma_f32_16x16x32_bf16(ah, bh, acc, 0, 0, 0);
  }
  // C/D: col = lane&15, row = quad*4 + reg  [verified R4-R8]
  if (!is_k) {
    #pragma unroll
    for (int reg = 0; reg < 4; ++reg) {
      int row = trow + quad * 4 + reg;
      qe[(size_t)row * Hn + wid * 16 + mr] = EXP2F(acc[reg] * TWO_LOG2E);
    }
  } else {
    #pragma unroll
    for (int reg = 0; reg < 4; ++reg)            // wave-private: no barrier
      tr[wid][mr][quad * 4 + reg] = EXP2F(acc[reg] * TWO_LOG2E);
    int b = trow >> 9, kr = trow & (KN - 1);
    #pragma unroll
    for (int hp = 0; hp < 4; ++hp) {
      int h_l = hp * 4 + quad, k_l = mr;
      ekT[((size_t)b * Hn + wid * 16 + h_l) * KN + kr + k_l] = tr[wid][h_l][k_l];
    }
  }
}

// Fused attention — R6's 61us structure (1024 blocks x 512 thr) + two fixes:
// (1) COMPLEMENTARY-RANK CU MAPPING: blocks {c, c+256, c+512, c+768} share a
//     CU under round-robin dispatch (R2/R6 behavior consistent with this).
//     Assign them L-rank batches {m, 15-m, (m+8)&15, 7-m} (two sorted-
//     complementary pairs) -> per-CU work ~ 4*mean(L), killing the 1.3x tail
//     WITHOUT halving blocks (R7's mistake). Wrong dispatch assumption ->
//     degrades to R6's random case; no downside.
// (2) PAIRED RECIPROCALS (R7-proven numerics): w_a/d_a + w_b/d_b =
//     (w_a*d_b + w_b*d_a) * rcp(d_a*d_b) -> 1 rcp per 2 h. d <= ~1e7 so
//     d_a*d_b <= ~1e14: safe in fp32.
// tanh(q+k) = 1 - 2/(Eq*Ek+1); softmax without max-subtraction
// (|score| <= sum|wv| ~ 7); PV 2-way k-split, col-per-thread.
__global__ __launch_bounds__(512) void attn_kernel(
    const float* __restrict__ qe,      // [B*512, 64]  exp2(C*q)
    const float* __restrict__ ekT,     // [B, 64, 512] exp2(C*k)
    const float* __restrict__ values,  // [B, 512, 256]
    const int*   __restrict__ valid_lens,
    const float* __restrict__ wv,      // [64]
    float* __restrict__ out)           // [B, 512, 256]
{
  __shared__ __align__(16) float qes2[Hn][TQ];   // 2 KB   [h][r]
  __shared__ __align__(16) float pt[KN][12];     // 24 KB  stride 12: 0 conflicts
  __shared__ __align__(16) float pacc[TQ][DV];   // 8 KB   upper-half PV partials
  __shared__ float wsum[8][TQ];
  __shared__ float inv_s[TQ];
  __shared__ int srank[Bn];

  int t = threadIdx.x;
  int lane = t & 63, wave = t >> 6;

  // ---- rank table: srank[r] = batch with r-th largest L ----
  if (t < Bn) {
    int Lb = valid_lens[t];
    int r = 0;
    #pragma unroll
    for (int b2 = 0; b2 < Bn; ++b2) {
      int L2 = valid_lens[b2];
      r += (L2 > Lb || (L2 == Lb && b2 < t)) ? 1 : 0;
    }
    srank[r] = t;
  }
  __syncthreads();

  // ---- complementary-rank mapping ----
  int cu = blockIdx.x & 255, slot = blockIdx.x >> 8;   // blocks cu+256*slot share a CU
  int m = cu >> 4;                                     // 0..15
  int jr = (slot == 0) ? m
         : (slot == 1) ? 15 - m
         : (slot == 2) ? ((m + 8) & 15)
                       : 15 - ((m + 8) & 15);
  int b = srank[jr];
  int q0 = (slot * 16 + (cu & 15)) * TQ;               // covers 0..63 per batch
  int L = valid_lens[b];

  qes2[t >> 3][t & 7] = qe[(size_t)(b * QN + q0 + (t & 7)) * Hn + (t >> 3)];
  __syncthreads();

  float S = 0.f;                                       // sum_h wv[h]
  #pragma unroll
  for (int h = 0; h < Hn; ++h) S += wv[h];

  // ---- scores: thread owns k = t ----
  {
    int k = t;
    float p[TQ];
    if (k < L) {
      float sc[TQ];
      #pragma unroll
      for (int r = 0; r < TQ; ++r) sc[r] = S;
      const float* kb = ekT + (size_t)b * Hn * KN + k;
      for (int h0 = 0; h0 < Hn; h0 += 8) {
        float ekv[8];
        #pragma unroll
        for (int j = 0; j < 8; ++j)                    // 8 loads in flight
          ekv[j] = kb[(size_t)(h0 + j) * KN];
        #pragma unroll
        for (int jp = 0; jp < 4; ++jp) {               // paired h: 1 rcp per 2 h
          int ha = h0 + 2 * jp;
          float wa = 2.0f * wv[ha], wb = 2.0f * wv[ha + 1];
          float eka = ekv[2 * jp], ekb = ekv[2 * jp + 1];
          float4 qa0 = *(const float4*)&qes2[ha][0];
          float4 qa1 = *(const float4*)&qes2[ha][4];
          float4 qb0 = *(const float4*)&qes2[ha + 1][0];
          float4 qb1 = *(const float4*)&qes2[ha + 1][4];
          float da, db, num;
          da = qa0.x * eka + 1.0f; db = qb0.x * ekb + 1.0f;
          num = wa * db + wb * da; sc[0] -= num * RCPF(da * db);
          da = qa0.y * eka + 1.0f; db = qb0.y * ekb + 1.0f;
          num = wa * db + wb * da; sc[1] -= num * RCPF(da * db);
          da = qa0.z * eka + 1.0f; db = qb0.z * ekb + 1.0f;
          num = wa * db + wb * da; sc[2] -= num * RCPF(da * db);
          da = qa0.w * eka + 1.0f; db = qb0.w * ekb + 1.0f;
          num = wa * db + wb * da; sc[3] -= num * RCPF(da * db);
          da = qa1.x * eka + 1.0f; db = qb1.x * ekb + 1.0f;
          num = wa * db + wb * da; sc[4] -= num * RCPF(da * db);
          da = qa1.y * eka + 1.0f; db = qb1.y * ekb + 1.0f;
          num = wa * db + wb * da; sc[5] -= num * RCPF(da * db);
          da = qa1.z * eka + 1.0f; db = qb1.z * ekb + 1.0f;
          num = wa * db + wb * da; sc[6] -= num * RCPF(da * db);
          da = qa1.w * eka + 1.0f; db = qb1.w * ekb + 1.0f;
          num = wa * db + wb * da; sc[7] -= num * RCPF(da * db);
        }
      }
      #pragma unroll
      for (int r = 0; r < TQ; ++r) p[r] = EXP2F(sc[r] * LOG2E);
      *(float4*)&pt[k][0] = make_float4(p[0], p[1], p[2], p[3]);
      *(float4*)&pt[k][4] = make_float4(p[4], p[5], p[6], p[7]);
    } else {
      #pragma unroll
      for (int r = 0; r < TQ; ++r) p[r] = 0.f;
    }
    #pragma unroll
    for (int r = 0; r < TQ; ++r) {                     // in-register row sums
      float s = p[r];
      #pragma unroll
      for (int off = 32; off > 0; off >>= 1) s += __shfl_xor(s, off, 64);
      if (lane == r) wsum[wave][r] = s;
    }
  }
  __syncthreads();
  if (t < TQ) {
    float s = 0.f;
    #pragma unroll
    for (int w = 0; w < 8; ++w) s += wsum[w][t];
    inv_s[t] = 1.0f / s;                               // read after pacc barrier
  }

  // ---- PV: thread owns col c = t&255, half of k (t>>8) ----
  int c = t & (DV - 1), half = t >> 8;
  int mid = L >> 1;
  int k0 = half ? mid : 0;
  int k1 = half ? L : mid;
  float acc[TQ];
  #pragma unroll
  for (int r = 0; r < TQ; ++r) acc[r] = 0.f;
  const float* vb = values + (size_t)b * KN * DV + c;
  #pragma unroll 4
  for (int k = k0; k < k1; ++k) {
    float val = vb[(size_t)k * DV];                    // coalesced
    float4 pa = *(const float4*)&pt[k][0];             // broadcast
    float4 pb = *(const float4*)&pt[k][4];
    acc[0] += pa.x * val; acc[1] += pa.y * val;
    acc[2] += pa.z * val; acc[3] += pa.w * val;
    acc[4] += pb.x * val; acc[5] += pb.y * val;
    acc[6] += pb.z * val; acc[7] += pb.w * val;
  }
  if (half) {
    #pragma unroll
    for (int r = 0; r < TQ; ++r) pacc[r][c] = acc[r];
  }
  __syncthreads();
  if (!half) {
    float* ob = out + (size_t)(b * QN + q0) * DV + c;
    #pragma unroll
    for (int r = 0; r < TQ; ++r)
      ob[(size_t)r * DV] = (acc[r] + pacc[r][c]) * inv_s[r];
  }
}

extern "C" void kernel_launch(void* const* d_in, const int* in_sizes, int n_in,
                              void* d_out, int out_size, void* d_ws, size_t ws_size,
                              hipStream_t stream) {
  const float* queries    = (const float*)d_in[0];
  const float* keys       = (const float*)d_in[1];
  const float* values     = (const float*)d_in[2];
  const int*   valid_lens = (const int*)d_in[3];
  const float* Wq         = (const float*)d_in[4];
  const float* Wk         = (const float*)d_in[5];
  const float* wv         = (const float*)d_in[6];
  float* out = (float*)d_out;

  char* ws = (char*)d_ws;
  float*  qe  = (float*)ws;                          // [8192][64] = 2 MB
  float*  ekT = qe + (size_t)Bn * QN * Hn;           // [B,64,512] = 2 MB
  ushort* wqh = (ushort*)(ekT + (size_t)Bn * Hn * KN);
  ushort* wql = wqh + Hn * DIN;                      // 4 x 32 KB
  ushort* wkh = wql + Hn * DIN;
  ushort* wkl = wkh + Hn * DIN;

  prep_kernel<<<64, 256, 0, stream>>>(Wq, Wk, wqh, wql, wkh, wkl);
  proj_mfma<<<1024, 256, 0, stream>>>(queries, keys, wqh, wql, wkh, wkl, qe, ekT);
  attn_kernel<<<Bn * (QN / TQ), 512, 0, stream>>>(qe, ekT, values,
                                                  valid_lens, wv, out);
}